// Round 5
// baseline (61.775 us; speedup 1.0000x reference)
//
#include <hip/hip_runtime.h>

#define BB 8
#define NN 2048
#define TT 64
#define DD 256
#define KK 128

// ---- per-block LDS spatial grid ----
#define GSZ 16
#define NC (GSZ * GSZ * GSZ)
#define DTHR 0.053f     // conservative per-dim candidate radius (covers fp error)
#define D2THR 0.0025f   // sqrt(max(d2,0)) < 0.05  <=>  d2 < 0.0025 (exact)

// ---------------------------------------------------------------------------
// One block per (b,t). Self-contained:
//   1. stage 2048 points (+ sq norms) into LDS, bbox via shfl+LDS reduce
//   2. build 16^3 linked-list grid entirely in LDS (atomicExch)
//   3. reflect each point, probe +-1 cell window, exact d2 check
// Numerics bit-identical to reference (validated rounds 2-4):
//   d2 = (rsq + pts_sq) - dot(2r, p), non-FMA, left-assoc; d2 < 0.0025f.
// Also copies this block's slice of the z_local passthrough.
// ---------------------------------------------------------------------------
__global__ __launch_bounds__(512) void detect_kernel(
    const float* __restrict__ points, const int* __restrict__ sample_idx,
    const float* __restrict__ z_local,
    int* __restrict__ counts, float* __restrict__ planes,
    float* __restrict__ out)
{
#pragma clang fp contract(off)
    __shared__ float4 spts[NN];              // 32 KB {x,y,z,||p||^2}
    __shared__ int    shead[NC];             // 16 KB
    __shared__ unsigned short snext[NN];     // 4 KB
    __shared__ float  sred[8][6];
    __shared__ float  g[6];                  // org[3], h[3]
    __shared__ int    blk_cnt;

    const int tid = threadIdx.x;
    const int bt  = blockIdx.x;
    const int b   = bt / TT;

    if (tid == 0) blk_cnt = 0;

    // z_local passthrough slice: 65536 float4 total / 512 blocks = 128 each
    if (tid < 128) {
        const float4* zl = (const float4*)z_local;
        float4* zo = (float4*)(out + BB * DD);
        zo[bt * 128 + tid] = zl[bt * 128 + tid];
    }

    const float* P = points + (size_t)b * NN * 3;

    // ---- stage + per-thread bbox ----
    float mnx = 3.4e38f, mny = 3.4e38f, mnz = 3.4e38f;
    float mxx = -3.4e38f, mxy = -3.4e38f, mxz = -3.4e38f;
#pragma unroll
    for (int k = 0; k < 4; ++k) {
        const int j = tid + k * 512;
        const float x = P[j * 3 + 0], y = P[j * 3 + 1], z = P[j * 3 + 2];
        spts[j] = make_float4(x, y, z, (x * x + y * y) + z * z);
        mnx = fminf(mnx, x); mxx = fmaxf(mxx, x);
        mny = fminf(mny, y); mxy = fmaxf(mxy, y);
        mnz = fminf(mnz, z); mxz = fmaxf(mxz, z);
    }
#pragma unroll
    for (int o = 32; o > 0; o >>= 1) {
        mnx = fminf(mnx, __shfl_xor(mnx, o));
        mny = fminf(mny, __shfl_xor(mny, o));
        mnz = fminf(mnz, __shfl_xor(mnz, o));
        mxx = fmaxf(mxx, __shfl_xor(mxx, o));
        mxy = fmaxf(mxy, __shfl_xor(mxy, o));
        mxz = fmaxf(mxz, __shfl_xor(mxz, o));
    }
    const int wave = tid >> 6;
    if ((tid & 63) == 0) {
        sred[wave][0] = mnx; sred[wave][1] = mny; sred[wave][2] = mnz;
        sred[wave][3] = mxx; sred[wave][4] = mxy; sred[wave][5] = mxz;
    }
    // head init (independent of the reduction)
    for (int c = tid; c < NC; c += 512) shead[c] = -1;
    __syncthreads();

    if (tid == 0) {
        float a0 = sred[0][0], a1 = sred[0][1], a2 = sred[0][2];
        float m3 = sred[0][3], m4 = sred[0][4], m5 = sred[0][5];
        for (int w = 1; w < 8; ++w) {
            a0 = fminf(a0, sred[w][0]); a1 = fminf(a1, sred[w][1]); a2 = fminf(a2, sred[w][2]);
            m3 = fmaxf(m3, sred[w][3]); m4 = fmaxf(m4, sred[w][4]); m5 = fmaxf(m5, sred[w][5]);
        }
        g[0] = a0 - 1e-3f; g[1] = a1 - 1e-3f; g[2] = a2 - 1e-3f;
        g[3] = fmaxf((m3 - g[0]) * (1.0f / 15.9f), 0.06f);
        g[4] = fmaxf((m4 - g[1]) * (1.0f / 15.9f), 0.06f);
        g[5] = fmaxf((m5 - g[2]) * (1.0f / 15.9f), 0.06f);
    }
    __syncthreads();
    const float ogx = g[0], ogy = g[1], ogz = g[2];
    const float hx = g[3], hy = g[4], hz = g[5];
    const float ivx = 1.0f / hx, ivy = 1.0f / hy, ivz = 1.0f / hz;

    // ---- insert points into LDS grid ----
#pragma unroll
    for (int k = 0; k < 4; ++k) {
        const int j = tid + k * 512;
        const float4 p = spts[j];
        int cx = (int)floorf((p.x - ogx) * ivx);
        int cy = (int)floorf((p.y - ogy) * ivy);
        int cz = (int)floorf((p.z - ogz) * ivz);
        cx = min(GSZ - 1, max(0, cx));
        cy = min(GSZ - 1, max(0, cy));
        cz = min(GSZ - 1, max(0, cz));
        const int cell = (cz * GSZ + cy) * GSZ + cx;
        const int old = atomicExch(&shead[cell], j);
        snext[j] = (unsigned short)old;   // -1 -> 0xFFFF sentinel
    }

    // ---- candidate plane (uniform across block) — exact reference ops ----
    const int i1 = sample_idx[bt * 2 + 0];
    const int i2 = sample_idx[bt * 2 + 1];
    const float q1x = P[i1 * 3 + 0], q1y = P[i1 * 3 + 1], q1z = P[i1 * 3 + 2];
    const float q2x = P[i2 * 3 + 0], q2y = P[i2 * 3 + 1], q2z = P[i2 * 3 + 2];
    const float dx0 = q2x - q1x, dy0 = q2y - q1y, dz0 = q2z - q1z;
    const float nd  = sqrtf((dx0 * dx0 + dy0 * dy0) + dz0 * dz0);
    const float den = nd + 1e-12f;
    const float nx = dx0 / den, ny = dy0 / den, nz = dz0 / den;
    const float e0 = (nx * (q1x + q2x)) * 0.5f;
    const float e1 = (ny * (q1y + q2y)) * 0.5f;
    const float e2 = (nz * (q1z + q2z)) * 0.5f;
    const float off = (e0 + e1) + e2;
    const float nnorm = sqrtf((nx * nx + ny * ny) + nz * nz);
    const float nden  = nnorm + 1e-12f;
    const float nnx = nx / nden, nny = ny / nden, nnz = nz / nden;

    __syncthreads();   // grid build complete

    // ---- reflect + grid-pruned exact NN match ----
    int cnt = 0;
#pragma unroll
    for (int q = 0; q < 4; ++q) {
        const int n = tid + q * 512;
        const float4 p = spts[n];
        const float sd = ((p.x * nnx + p.y * nny) + p.z * nnz) - off;
        const float s  = 2.0f * sd;
        const float rx = p.x - s * nnx;
        const float ry = p.y - s * nny;
        const float rz = p.z - s * nnz;
        const float rsq = (rx * rx + ry * ry) + rz * rz;
        const float r2x = rx + rx, r2y = ry + ry, r2z = rz + rz; // exact *2

        const float tx = rx - ogx; const float cfx = floorf(tx * ivx);
        const float ty = ry - ogy; const float cfy = floorf(ty * ivy);
        const float tz = rz - ogz; const float cfz = floorf(tz * ivz);
        const int cxi = (int)cfx, cyi = (int)cfy, czi = (int)cfz;
        const float fx = tx - cfx * hx;
        const float fy = ty - cfy * hy;
        const float fz = tz - cfz * hz;
        const int lx = (fx < DTHR) ? -1 : 0, ux = (fx > hx - DTHR) ? 1 : 0;
        const int ly = (fy < DTHR) ? -1 : 0, uy = (fy > hy - DTHR) ? 1 : 0;
        const int lz = (fz < DTHR) ? -1 : 0, uz = (fz > hz - DTHR) ? 1 : 0;

        int matched = 0;
        for (int dz = lz; dz <= uz && !matched; ++dz) {
            const int cz = czi + dz; if ((unsigned)cz >= GSZ) continue;
            for (int dy = ly; dy <= uy && !matched; ++dy) {
                const int cy = cyi + dy; if ((unsigned)cy >= GSZ) continue;
                for (int dxi = lx; dxi <= ux && !matched; ++dxi) {
                    const int cx = cxi + dxi; if ((unsigned)cx >= GSZ) continue;
                    int j = shead[(cz * GSZ + cy) * GSZ + cx];
                    while (j >= 0) {
                        const float4 pm = spts[j];
                        const float c2 = (r2x * pm.x + r2y * pm.y) + r2z * pm.z;
                        const float t1 = rsq + pm.w;
                        matched |= ((t1 - c2) < D2THR) ? 1 : 0;
                        const unsigned short nj = snext[j];
                        j = (nj == 0xFFFFu) ? -1 : (int)nj;
                    }
                }
            }
        }
        cnt += matched;
    }

    for (int o = 32; o > 0; o >>= 1) cnt += __shfl_down(cnt, o);
    if ((tid & 63) == 0) atomicAdd(&blk_cnt, cnt);
    __syncthreads();

    if (tid == 0) {
        counts[bt] = blk_cnt;
        planes[bt * 5 + 0] = nx;
        planes[bt * 5 + 1] = ny;
        planes[bt * 5 + 2] = nz;
        planes[bt * 5 + 3] = off;
        planes[bt * 5 + 4] = nd;
    }
}

// ---------------------------------------------------------------------------
// Kernel 2: per-batch argmax (first-wins), centroid, GEMV, small outputs.
// ---------------------------------------------------------------------------
__global__ __launch_bounds__(256) void finalize_kernel(
    const float* __restrict__ points, const float* __restrict__ z_enc,
    const float* __restrict__ Wm, const float* __restrict__ bias,
    const int* __restrict__ counts, const float* __restrict__ planes,
    float* __restrict__ out)
{
    const int b = blockIdx.x, tid = threadIdx.x;
    __shared__ float zaug[DD + 4];
    __shared__ float red[3][256];

    const float* P = points + (size_t)b * NN * 3;
    float sx = 0.f, sy = 0.f, sz = 0.f;
    for (int j = tid; j < NN; j += 256) {
        sx += P[j*3]; sy += P[j*3+1]; sz += P[j*3+2];
    }
    red[0][tid] = sx; red[1][tid] = sy; red[2][tid] = sz;
    zaug[tid] = z_enc[b * DD + tid];
    __syncthreads();
    for (int s = 128; s > 0; s >>= 1) {
        if (tid < s) {
            red[0][tid] += red[0][tid + s];
            red[1][tid] += red[1][tid + s];
            red[2][tid] += red[2][tid + s];
        }
        __syncthreads();
    }
    if (tid == 0) {
        const float cx = red[0][0] / (float)NN;
        const float cy = red[1][0] / (float)NN;
        const float cz = red[2][0] / (float)NN;
        float bn0 = 0.f, bn1 = 1.f, bn2 = 0.f, bo = 0.f, bc = 0.f;
        for (int t = 0; t < TT; ++t) {
            const int bt = b * TT + t;
            const float ndv = planes[bt * 5 + 4];
            const float frac = (ndv < 1e-8f) ? -1.0f
                               : (float)counts[bt] * (1.0f / 2048.0f);
            if (frac > bc) {
                bn0 = planes[bt*5+0]; bn1 = planes[bt*5+1]; bn2 = planes[bt*5+2];
                bo = planes[bt*5+3]; bc = frac;
            }
        }
        const float sd = ((bn0 * cx + bn1 * cy) + bn2 * cz) - bo;
        zaug[DD + 0] = bn0; zaug[DD + 1] = bn1; zaug[DD + 2] = bn2; zaug[DD + 3] = sd;
        float* normals = out + (BB * DD + BB * KK * DD);
        normals[b*3+0] = bn0; normals[b*3+1] = bn1; normals[b*3+2] = bn2;
        float* offs = normals + BB * 3;
        offs[b] = bo;
        float* conf = offs + BB;
        conf[b] = bc;
    }
    __syncthreads();
    const float* wrow = Wm + (size_t)tid * (DD + 4);
    float acc = bias[tid];
    for (int j = 0; j < DD + 4; ++j) acc += zaug[j] * wrow[j];
    out[b * DD + tid] = acc;
}

extern "C" void kernel_launch(void* const* d_in, const int* in_sizes, int n_in,
                              void* d_out, int out_size, void* d_ws, size_t ws_size,
                              hipStream_t stream) {
    const float* points     = (const float*)d_in[0];
    const float* z_enc      = (const float*)d_in[1];
    const float* z_local    = (const float*)d_in[2];
    // d_in[3] = proxy_coords (unused by reference outputs)
    const int*   sample_idx = (const int*)d_in[4];
    const float* Wm         = (const float*)d_in[5];
    const float* bias       = (const float*)d_in[6];
    float* out = (float*)d_out;

    char* wsb = (char*)d_ws;
    int*   counts = (int*)(wsb + 0);                 // BB*TT ints
    float* planes = (float*)(wsb + BB * TT * 4);     // BB*TT*5 floats

    detect_kernel<<<BB * TT, 512, 0, stream>>>(
        points, sample_idx, z_local, counts, planes, out);
    finalize_kernel<<<BB, 256, 0, stream>>>(
        points, z_enc, Wm, bias, counts, planes, out);
}

// Round 6
// 54.782 us; speedup vs baseline: 1.1276x; 1.1276x over previous
//
#include <hip/hip_runtime.h>

#define BB 8
#define NN 2048
#define TT 64
#define DD 256
#define KK 128

// ---- per-block LDS counting-sort grid ----
#define GSZ 16
#define NC (GSZ * GSZ * GSZ)
#define DTHR 0.053f     // conservative per-dim candidate radius (covers fp error)
#define D2THR 0.0025f   // sqrt(max(d2,0)) < 0.05  <=>  d2 < 0.0025 (exact)

// ---------------------------------------------------------------------------
// One block per (b,t). Self-contained, pointer-free:
//   1. load 4 pts/thread into REGISTERS, bbox via shfl+LDS reduce
//   2. histogram -> exclusive prefix sum -> scatter: cell-sorted sp[] in LDS
//   3. reflect each register point, scan <=4 contiguous candidate ranges,
//      exact d2 check (bit-identical to reference, validated r2-r5)
// Also copies this block's slice of the z_local passthrough.
// ---------------------------------------------------------------------------
__global__ __launch_bounds__(512) void detect_kernel(
    const float* __restrict__ points, const int* __restrict__ sample_idx,
    const float* __restrict__ z_local,
    int* __restrict__ counts, float* __restrict__ planes,
    float* __restrict__ out)
{
#pragma clang fp contract(off)
    __shared__ float4 sp[NN];        // 32 KB cell-sorted {x,y,z,||p||^2}
    __shared__ int    cellofs[NC];   // 16 KB: hist -> excl start -> end offset
    __shared__ float  sred[8][6];
    __shared__ int    swsum[8];
    __shared__ float  g[6];          // org[3], h[3]
    __shared__ int    blk_cnt;

    const int tid  = threadIdx.x;
    const int lane = tid & 63;
    const int wav  = tid >> 6;
    const int bt   = blockIdx.x;
    const int b    = bt / TT;

    if (tid == 0) blk_cnt = 0;

    // z_local passthrough slice: 65536 float4 total / 512 blocks = 128 each
    if (tid < 128) {
        const float4* zl = (const float4*)z_local;
        float4* zo = (float4*)(out + BB * DD);
        zo[bt * 128 + tid] = zl[bt * 128 + tid];
    }

    const float* P = points + (size_t)b * NN * 3;

    // ---- load 4 points/thread to registers + bbox ----
    float px[4], py[4], pz[4], ps[4];
    float mnx = 3.4e38f, mny = 3.4e38f, mnz = 3.4e38f;
    float mxx = -3.4e38f, mxy = -3.4e38f, mxz = -3.4e38f;
#pragma unroll
    for (int k = 0; k < 4; ++k) {
        const int j = tid + k * 512;
        const float x = P[j * 3 + 0], y = P[j * 3 + 1], z = P[j * 3 + 2];
        px[k] = x; py[k] = y; pz[k] = z;
        ps[k] = (x * x + y * y) + z * z;   // matches pts_sq op order
        mnx = fminf(mnx, x); mxx = fmaxf(mxx, x);
        mny = fminf(mny, y); mxy = fmaxf(mxy, y);
        mnz = fminf(mnz, z); mxz = fmaxf(mxz, z);
    }
#pragma unroll
    for (int o = 32; o > 0; o >>= 1) {
        mnx = fminf(mnx, __shfl_xor(mnx, o));
        mny = fminf(mny, __shfl_xor(mny, o));
        mnz = fminf(mnz, __shfl_xor(mnz, o));
        mxx = fmaxf(mxx, __shfl_xor(mxx, o));
        mxy = fmaxf(mxy, __shfl_xor(mxy, o));
        mxz = fmaxf(mxz, __shfl_xor(mxz, o));
    }
    if (lane == 0) {
        sred[wav][0] = mnx; sred[wav][1] = mny; sred[wav][2] = mnz;
        sred[wav][3] = mxx; sred[wav][4] = mxy; sred[wav][5] = mxz;
    }
    // zero histogram (independent of the reduction)
    for (int c = tid; c < NC; c += 512) cellofs[c] = 0;
    __syncthreads();

    if (tid == 0) {
        float a0 = sred[0][0], a1 = sred[0][1], a2 = sred[0][2];
        float m3 = sred[0][3], m4 = sred[0][4], m5 = sred[0][5];
        for (int w = 1; w < 8; ++w) {
            a0 = fminf(a0, sred[w][0]); a1 = fminf(a1, sred[w][1]); a2 = fminf(a2, sred[w][2]);
            m3 = fmaxf(m3, sred[w][3]); m4 = fmaxf(m4, sred[w][4]); m5 = fmaxf(m5, sred[w][5]);
        }
        g[0] = a0 - 1e-3f; g[1] = a1 - 1e-3f; g[2] = a2 - 1e-3f;
        g[3] = fmaxf((m3 - g[0]) * (1.0f / 15.9f), 0.06f);
        g[4] = fmaxf((m4 - g[1]) * (1.0f / 15.9f), 0.06f);
        g[5] = fmaxf((m5 - g[2]) * (1.0f / 15.9f), 0.06f);
    }
    __syncthreads();
    const float ogx = g[0], ogy = g[1], ogz = g[2];
    const float hx = g[3], hy = g[4], hz = g[5];
    const float ivx = 1.0f / hx, ivy = 1.0f / hy, ivz = 1.0f / hz;

    // ---- histogram ----
    int cell[4];
#pragma unroll
    for (int k = 0; k < 4; ++k) {
        int cx = (int)floorf((px[k] - ogx) * ivx);
        int cy = (int)floorf((py[k] - ogy) * ivy);
        int cz = (int)floorf((pz[k] - ogz) * ivz);
        cx = min(GSZ - 1, max(0, cx));
        cy = min(GSZ - 1, max(0, cy));
        cz = min(GSZ - 1, max(0, cz));
        cell[k] = (cz * GSZ + cy) * GSZ + cx;
        atomicAdd(&cellofs[cell[k]], 1);
    }
    __syncthreads();

    // ---- exclusive prefix sum over NC=4096 cells (8 per thread) ----
    const int base = tid * 8;
    int loc[8];
    int tsum = 0;
#pragma unroll
    for (int k = 0; k < 8; ++k) {
        loc[k] = tsum;                 // thread-local exclusive
        tsum += cellofs[base + k];
    }
    int inc = tsum;                    // inclusive wave scan of thread sums
#pragma unroll
    for (int o = 1; o < 64; o <<= 1) {
        const int v = __shfl_up(inc, o);
        if (lane >= o) inc += v;
    }
    if (lane == 63) swsum[wav] = inc;
    __syncthreads();
    if (tid == 0) {
        int r = 0;
        for (int w = 0; w < 8; ++w) { const int t = swsum[w]; swsum[w] = r; r += t; }
    }
    __syncthreads();
    const int texcl = (inc - tsum) + swsum[wav];   // exclusive over threads
#pragma unroll
    for (int k = 0; k < 8; ++k) cellofs[base + k] = texcl + loc[k];  // excl starts
    __syncthreads();

    // ---- scatter: cellofs[c] becomes END offset after all inserts ----
#pragma unroll
    for (int k = 0; k < 4; ++k) {
        const int pos = atomicAdd(&cellofs[cell[k]], 1);
        sp[pos] = make_float4(px[k], py[k], pz[k], ps[k]);
    }

    // ---- candidate plane (uniform across block) — exact reference ops ----
    const int i1 = sample_idx[bt * 2 + 0];
    const int i2 = sample_idx[bt * 2 + 1];
    const float q1x = P[i1 * 3 + 0], q1y = P[i1 * 3 + 1], q1z = P[i1 * 3 + 2];
    const float q2x = P[i2 * 3 + 0], q2y = P[i2 * 3 + 1], q2z = P[i2 * 3 + 2];
    const float dx0 = q2x - q1x, dy0 = q2y - q1y, dz0 = q2z - q1z;
    const float nd  = sqrtf((dx0 * dx0 + dy0 * dy0) + dz0 * dz0);
    const float den = nd + 1e-12f;
    const float nx = dx0 / den, ny = dy0 / den, nz = dz0 / den;
    const float e0 = (nx * (q1x + q2x)) * 0.5f;
    const float e1 = (ny * (q1y + q2y)) * 0.5f;
    const float e2 = (nz * (q1z + q2z)) * 0.5f;
    const float off = (e0 + e1) + e2;
    const float nnorm = sqrtf((nx * nx + ny * ny) + nz * nz);
    const float nden  = nnorm + 1e-12f;
    const float nnx = nx / nden, nny = ny / nden, nnz = nz / nden;

    __syncthreads();   // sorted grid complete

    // ---- reflect + range-scan exact NN match ----
    int cnt = 0;
#pragma unroll
    for (int k = 0; k < 4; ++k) {
        const float sd = ((px[k] * nnx + py[k] * nny) + pz[k] * nnz) - off;
        const float s  = 2.0f * sd;
        const float rx = px[k] - s * nnx;
        const float ry = py[k] - s * nny;
        const float rz = pz[k] - s * nnz;
        const float rsq = (rx * rx + ry * ry) + rz * rz;
        const float r2x = rx + rx, r2y = ry + ry, r2z = rz + rz; // exact *2

        const float tx = rx - ogx; const float cfx = floorf(tx * ivx);
        const float ty = ry - ogy; const float cfy = floorf(ty * ivy);
        const float tz = rz - ogz; const float cfz = floorf(tz * ivz);
        const int cxi = (int)cfx, cyi = (int)cfy, czi = (int)cfz;
        const float fx = tx - cfx * hx;
        const float fy = ty - cfy * hy;
        const float fz = tz - cfz * hz;
        // x-window as one contiguous cell-index range
        const int cx0 = max(0, cxi + ((fx < DTHR) ? -1 : 0));
        const int cx1 = min(GSZ - 1, cxi + ((fx > hx - DTHR) ? 1 : 0));
        const int ly = (fy < DTHR) ? -1 : 0, uy = (fy > hy - DTHR) ? 1 : 0;
        const int lz = (fz < DTHR) ? -1 : 0, uz = (fz > hz - DTHR) ? 1 : 0;

        int matched = 0;
        if (cx0 <= cx1) {
            for (int dz = lz; dz <= uz; ++dz) {
                const int cz = czi + dz; if ((unsigned)cz >= GSZ) continue;
                for (int dy = ly; dy <= uy; ++dy) {
                    const int cy = cyi + dy; if ((unsigned)cy >= GSZ) continue;
                    const int rowbase = (cz * GSZ + cy) * GSZ;
                    const int idx0 = rowbase + cx0;
                    const int idx1 = rowbase + cx1;
                    const int jb = (idx0 == 0) ? 0 : cellofs[idx0 - 1];
                    const int je = cellofs[idx1];
                    for (int j = jb; j < je; ++j) {
                        const float4 pm = sp[j];
                        const float c2 = (r2x * pm.x + r2y * pm.y) + r2z * pm.z;
                        const float t1 = rsq + pm.w;
                        matched |= ((t1 - c2) < D2THR) ? 1 : 0;
                    }
                }
            }
        }
        cnt += matched;
    }

    for (int o = 32; o > 0; o >>= 1) cnt += __shfl_down(cnt, o);
    if (lane == 0) atomicAdd(&blk_cnt, cnt);
    __syncthreads();

    if (tid == 0) {
        counts[bt] = blk_cnt;
        planes[bt * 5 + 0] = nx;
        planes[bt * 5 + 1] = ny;
        planes[bt * 5 + 2] = nz;
        planes[bt * 5 + 3] = off;
        planes[bt * 5 + 4] = nd;
    }
}

// ---------------------------------------------------------------------------
// Kernel 2: per-batch argmax (first-wins), centroid, GEMV, small outputs.
// ---------------------------------------------------------------------------
__global__ __launch_bounds__(256) void finalize_kernel(
    const float* __restrict__ points, const float* __restrict__ z_enc,
    const float* __restrict__ Wm, const float* __restrict__ bias,
    const int* __restrict__ counts, const float* __restrict__ planes,
    float* __restrict__ out)
{
    const int b = blockIdx.x, tid = threadIdx.x;
    __shared__ float zaug[DD + 4];
    __shared__ float red[3][256];

    const float* P = points + (size_t)b * NN * 3;
    float sx = 0.f, sy = 0.f, sz = 0.f;
    for (int j = tid; j < NN; j += 256) {
        sx += P[j*3]; sy += P[j*3+1]; sz += P[j*3+2];
    }
    red[0][tid] = sx; red[1][tid] = sy; red[2][tid] = sz;
    zaug[tid] = z_enc[b * DD + tid];
    __syncthreads();
    for (int s = 128; s > 0; s >>= 1) {
        if (tid < s) {
            red[0][tid] += red[0][tid + s];
            red[1][tid] += red[1][tid + s];
            red[2][tid] += red[2][tid + s];
        }
        __syncthreads();
    }
    if (tid == 0) {
        const float cx = red[0][0] / (float)NN;
        const float cy = red[1][0] / (float)NN;
        const float cz = red[2][0] / (float)NN;
        float bn0 = 0.f, bn1 = 1.f, bn2 = 0.f, bo = 0.f, bc = 0.f;
        for (int t = 0; t < TT; ++t) {
            const int bt = b * TT + t;
            const float ndv = planes[bt * 5 + 4];
            const float frac = (ndv < 1e-8f) ? -1.0f
                               : (float)counts[bt] * (1.0f / 2048.0f);
            if (frac > bc) {
                bn0 = planes[bt*5+0]; bn1 = planes[bt*5+1]; bn2 = planes[bt*5+2];
                bo = planes[bt*5+3]; bc = frac;
            }
        }
        const float sd = ((bn0 * cx + bn1 * cy) + bn2 * cz) - bo;
        zaug[DD + 0] = bn0; zaug[DD + 1] = bn1; zaug[DD + 2] = bn2; zaug[DD + 3] = sd;
        float* normals = out + (BB * DD + BB * KK * DD);
        normals[b*3+0] = bn0; normals[b*3+1] = bn1; normals[b*3+2] = bn2;
        float* offs = normals + BB * 3;
        offs[b] = bo;
        float* conf = offs + BB;
        conf[b] = bc;
    }
    __syncthreads();
    const float* wrow = Wm + (size_t)tid * (DD + 4);
    float acc = bias[tid];
    for (int j = 0; j < DD + 4; ++j) acc += zaug[j] * wrow[j];
    out[b * DD + tid] = acc;
}

extern "C" void kernel_launch(void* const* d_in, const int* in_sizes, int n_in,
                              void* d_out, int out_size, void* d_ws, size_t ws_size,
                              hipStream_t stream) {
    const float* points     = (const float*)d_in[0];
    const float* z_enc      = (const float*)d_in[1];
    const float* z_local    = (const float*)d_in[2];
    // d_in[3] = proxy_coords (unused by reference outputs)
    const int*   sample_idx = (const int*)d_in[4];
    const float* Wm         = (const float*)d_in[5];
    const float* bias       = (const float*)d_in[6];
    float* out = (float*)d_out;

    char* wsb = (char*)d_ws;
    int*   counts = (int*)(wsb + 0);                 // BB*TT ints
    float* planes = (float*)(wsb + BB * TT * 4);     // BB*TT*5 floats

    detect_kernel<<<BB * TT, 512, 0, stream>>>(
        points, sample_idx, z_local, counts, planes, out);
    finalize_kernel<<<BB, 256, 0, stream>>>(
        points, z_enc, Wm, bias, counts, planes, out);
}

// Round 7
// 51.276 us; speedup vs baseline: 1.2048x; 1.0684x over previous
//
#include <hip/hip_runtime.h>

#define BB 8
#define NN 2048
#define TT 64
#define DD 256
#define KK 128

// ---- per-block LDS counting-sort grid ----
#define GSZ 16
#define NC (GSZ * GSZ * GSZ)
#define DTHR 0.053f     // conservative per-dim candidate radius (covers fp error)
#define D2THR 0.0025f   // sqrt(max(d2,0)) < 0.05  <=>  d2 < 0.0025 (exact)

// ---------------------------------------------------------------------------
// One block per (b,t). Self-contained, pointer-free:
//   1. load 4 pts/thread into registers, bbox via shfl+LDS reduce
//   2. histogram -> exclusive prefix sum -> scatter: cell-sorted sp[] in LDS
//   3. queries iterate sp[] IN SORTED ORDER: adjacent lanes share cells, so
//      windows/ranges correlate (no divergence) and candidate reads broadcast
//   4. exact d2 check (bit-identical to reference, validated r2-r6)
// Count is order-independent (sum of per-point flags over a permutation).
// Also copies this block's slice of the z_local passthrough.
// ---------------------------------------------------------------------------
__global__ __launch_bounds__(512) void detect_kernel(
    const float* __restrict__ points, const int* __restrict__ sample_idx,
    const float* __restrict__ z_local,
    int* __restrict__ counts, float* __restrict__ planes,
    float* __restrict__ out)
{
#pragma clang fp contract(off)
    __shared__ float4 sp[NN];        // 32 KB cell-sorted {x,y,z,||p||^2}
    __shared__ int    cellofs[NC];   // 16 KB: hist -> excl start -> end offset
    __shared__ float  sred[8][6];
    __shared__ int    swsum[8];
    __shared__ float  g[6];          // org[3], h[3]
    __shared__ int    blk_cnt;

    const int tid  = threadIdx.x;
    const int lane = tid & 63;
    const int wav  = tid >> 6;
    const int bt   = blockIdx.x;
    const int b    = bt / TT;

    if (tid == 0) blk_cnt = 0;

    // z_local passthrough slice: 65536 float4 total / 512 blocks = 128 each
    if (tid < 128) {
        const float4* zl = (const float4*)z_local;
        float4* zo = (float4*)(out + BB * DD);
        zo[bt * 128 + tid] = zl[bt * 128 + tid];
    }

    const float* P = points + (size_t)b * NN * 3;

    // ---- load 4 points/thread to registers + bbox ----
    float px[4], py[4], pz[4], ps[4];
    float mnx = 3.4e38f, mny = 3.4e38f, mnz = 3.4e38f;
    float mxx = -3.4e38f, mxy = -3.4e38f, mxz = -3.4e38f;
#pragma unroll
    for (int k = 0; k < 4; ++k) {
        const int j = tid + k * 512;
        const float x = P[j * 3 + 0], y = P[j * 3 + 1], z = P[j * 3 + 2];
        px[k] = x; py[k] = y; pz[k] = z;
        ps[k] = (x * x + y * y) + z * z;   // matches pts_sq op order
        mnx = fminf(mnx, x); mxx = fmaxf(mxx, x);
        mny = fminf(mny, y); mxy = fmaxf(mxy, y);
        mnz = fminf(mnz, z); mxz = fmaxf(mxz, z);
    }
#pragma unroll
    for (int o = 32; o > 0; o >>= 1) {
        mnx = fminf(mnx, __shfl_xor(mnx, o));
        mny = fminf(mny, __shfl_xor(mny, o));
        mnz = fminf(mnz, __shfl_xor(mnz, o));
        mxx = fmaxf(mxx, __shfl_xor(mxx, o));
        mxy = fmaxf(mxy, __shfl_xor(mxy, o));
        mxz = fmaxf(mxz, __shfl_xor(mxz, o));
    }
    if (lane == 0) {
        sred[wav][0] = mnx; sred[wav][1] = mny; sred[wav][2] = mnz;
        sred[wav][3] = mxx; sred[wav][4] = mxy; sred[wav][5] = mxz;
    }
    // zero histogram (independent of the reduction)
    for (int c = tid; c < NC; c += 512) cellofs[c] = 0;
    __syncthreads();

    if (tid == 0) {
        float a0 = sred[0][0], a1 = sred[0][1], a2 = sred[0][2];
        float m3 = sred[0][3], m4 = sred[0][4], m5 = sred[0][5];
        for (int w = 1; w < 8; ++w) {
            a0 = fminf(a0, sred[w][0]); a1 = fminf(a1, sred[w][1]); a2 = fminf(a2, sred[w][2]);
            m3 = fmaxf(m3, sred[w][3]); m4 = fmaxf(m4, sred[w][4]); m5 = fmaxf(m5, sred[w][5]);
        }
        g[0] = a0 - 1e-3f; g[1] = a1 - 1e-3f; g[2] = a2 - 1e-3f;
        g[3] = fmaxf((m3 - g[0]) * (1.0f / 15.9f), 0.06f);
        g[4] = fmaxf((m4 - g[1]) * (1.0f / 15.9f), 0.06f);
        g[5] = fmaxf((m5 - g[2]) * (1.0f / 15.9f), 0.06f);
    }
    __syncthreads();
    const float ogx = g[0], ogy = g[1], ogz = g[2];
    const float hx = g[3], hy = g[4], hz = g[5];
    const float ivx = 1.0f / hx, ivy = 1.0f / hy, ivz = 1.0f / hz;

    // ---- histogram ----
    int cell[4];
#pragma unroll
    for (int k = 0; k < 4; ++k) {
        int cx = (int)floorf((px[k] - ogx) * ivx);
        int cy = (int)floorf((py[k] - ogy) * ivy);
        int cz = (int)floorf((pz[k] - ogz) * ivz);
        cx = min(GSZ - 1, max(0, cx));
        cy = min(GSZ - 1, max(0, cy));
        cz = min(GSZ - 1, max(0, cz));
        cell[k] = (cz * GSZ + cy) * GSZ + cx;
        atomicAdd(&cellofs[cell[k]], 1);
    }
    __syncthreads();

    // ---- exclusive prefix sum over NC=4096 cells (8 per thread) ----
    const int base = tid * 8;
    int loc[8];
    int tsum = 0;
#pragma unroll
    for (int k = 0; k < 8; ++k) {
        loc[k] = tsum;                 // thread-local exclusive
        tsum += cellofs[base + k];
    }
    int inc = tsum;                    // inclusive wave scan of thread sums
#pragma unroll
    for (int o = 1; o < 64; o <<= 1) {
        const int v = __shfl_up(inc, o);
        if (lane >= o) inc += v;
    }
    if (lane == 63) swsum[wav] = inc;
    __syncthreads();
    if (tid == 0) {
        int r = 0;
        for (int w = 0; w < 8; ++w) { const int t = swsum[w]; swsum[w] = r; r += t; }
    }
    __syncthreads();
    const int texcl = (inc - tsum) + swsum[wav];   // exclusive over threads
#pragma unroll
    for (int k = 0; k < 8; ++k) cellofs[base + k] = texcl + loc[k];  // excl starts
    __syncthreads();

    // ---- scatter: cellofs[c] becomes END offset after all inserts ----
#pragma unroll
    for (int k = 0; k < 4; ++k) {
        const int pos = atomicAdd(&cellofs[cell[k]], 1);
        sp[pos] = make_float4(px[k], py[k], pz[k], ps[k]);
    }

    // ---- candidate plane (uniform across block) — exact reference ops ----
    const int i1 = sample_idx[bt * 2 + 0];
    const int i2 = sample_idx[bt * 2 + 1];
    const float q1x = P[i1 * 3 + 0], q1y = P[i1 * 3 + 1], q1z = P[i1 * 3 + 2];
    const float q2x = P[i2 * 3 + 0], q2y = P[i2 * 3 + 1], q2z = P[i2 * 3 + 2];
    const float dx0 = q2x - q1x, dy0 = q2y - q1y, dz0 = q2z - q1z;
    const float nd  = sqrtf((dx0 * dx0 + dy0 * dy0) + dz0 * dz0);
    const float den = nd + 1e-12f;
    const float nx = dx0 / den, ny = dy0 / den, nz = dz0 / den;
    const float e0 = (nx * (q1x + q2x)) * 0.5f;
    const float e1 = (ny * (q1y + q2y)) * 0.5f;
    const float e2 = (nz * (q1z + q2z)) * 0.5f;
    const float off = (e0 + e1) + e2;
    const float nnorm = sqrtf((nx * nx + ny * ny) + nz * nz);
    const float nden  = nnorm + 1e-12f;
    const float nnx = nx / nden, nny = ny / nden, nnz = nz / nden;

    __syncthreads();   // sorted grid complete

    // ---- queries in SORTED order: reflect + range-scan exact NN match ----
    int cnt = 0;
#pragma unroll
    for (int k = 0; k < 4; ++k) {
        const int n = tid + k * 512;
        const float4 q = sp[n];        // sorted: adjacent lanes share cells
        const float sd = ((q.x * nnx + q.y * nny) + q.z * nnz) - off;
        const float s  = 2.0f * sd;
        const float rx = q.x - s * nnx;
        const float ry = q.y - s * nny;
        const float rz = q.z - s * nnz;
        const float rsq = (rx * rx + ry * ry) + rz * rz;
        const float r2x = rx + rx, r2y = ry + ry, r2z = rz + rz; // exact *2

        const float tx = rx - ogx; const float cfx = floorf(tx * ivx);
        const float ty = ry - ogy; const float cfy = floorf(ty * ivy);
        const float tz = rz - ogz; const float cfz = floorf(tz * ivz);
        const int cxi = (int)cfx, cyi = (int)cfy, czi = (int)cfz;
        const float fx = tx - cfx * hx;
        const float fy = ty - cfy * hy;
        const float fz = tz - cfz * hz;
        // x-window as one contiguous cell-index range
        const int cx0 = max(0, cxi + ((fx < DTHR) ? -1 : 0));
        const int cx1 = min(GSZ - 1, cxi + ((fx > hx - DTHR) ? 1 : 0));
        const int ly = (fy < DTHR) ? -1 : 0, uy = (fy > hy - DTHR) ? 1 : 0;
        const int lz = (fz < DTHR) ? -1 : 0, uz = (fz > hz - DTHR) ? 1 : 0;

        int matched = 0;
        if (cx0 <= cx1) {
            for (int dz = lz; dz <= uz; ++dz) {
                const int cz = czi + dz; if ((unsigned)cz >= GSZ) continue;
                for (int dy = ly; dy <= uy; ++dy) {
                    const int cy = cyi + dy; if ((unsigned)cy >= GSZ) continue;
                    const int rowbase = (cz * GSZ + cy) * GSZ;
                    const int idx0 = rowbase + cx0;
                    const int idx1 = rowbase + cx1;
                    const int jb = (idx0 == 0) ? 0 : cellofs[idx0 - 1];
                    const int je = cellofs[idx1];
                    for (int j = jb; j < je; ++j) {
                        const float4 pm = sp[j];
                        const float c2 = (r2x * pm.x + r2y * pm.y) + r2z * pm.z;
                        const float t1 = rsq + pm.w;
                        matched |= ((t1 - c2) < D2THR) ? 1 : 0;
                    }
                }
            }
        }
        cnt += matched;
    }

    for (int o = 32; o > 0; o >>= 1) cnt += __shfl_down(cnt, o);
    if (lane == 0) atomicAdd(&blk_cnt, cnt);
    __syncthreads();

    if (tid == 0) {
        counts[bt] = blk_cnt;
        planes[bt * 5 + 0] = nx;
        planes[bt * 5 + 1] = ny;
        planes[bt * 5 + 2] = nz;
        planes[bt * 5 + 3] = off;
        planes[bt * 5 + 4] = nd;
    }
}

// ---------------------------------------------------------------------------
// Kernel 2: per-batch argmax (first-wins), centroid, GEMV, small outputs.
// ---------------------------------------------------------------------------
__global__ __launch_bounds__(256) void finalize_kernel(
    const float* __restrict__ points, const float* __restrict__ z_enc,
    const float* __restrict__ Wm, const float* __restrict__ bias,
    const int* __restrict__ counts, const float* __restrict__ planes,
    float* __restrict__ out)
{
    const int b = blockIdx.x, tid = threadIdx.x;
    __shared__ float zaug[DD + 4];
    __shared__ float red[3][256];

    const float* P = points + (size_t)b * NN * 3;
    float sx = 0.f, sy = 0.f, sz = 0.f;
    for (int j = tid; j < NN; j += 256) {
        sx += P[j*3]; sy += P[j*3+1]; sz += P[j*3+2];
    }
    red[0][tid] = sx; red[1][tid] = sy; red[2][tid] = sz;
    zaug[tid] = z_enc[b * DD + tid];
    __syncthreads();
    for (int s = 128; s > 0; s >>= 1) {
        if (tid < s) {
            red[0][tid] += red[0][tid + s];
            red[1][tid] += red[1][tid + s];
            red[2][tid] += red[2][tid + s];
        }
        __syncthreads();
    }
    if (tid == 0) {
        const float cx = red[0][0] / (float)NN;
        const float cy = red[1][0] / (float)NN;
        const float cz = red[2][0] / (float)NN;
        float bn0 = 0.f, bn1 = 1.f, bn2 = 0.f, bo = 0.f, bc = 0.f;
        for (int t = 0; t < TT; ++t) {
            const int bt = b * TT + t;
            const float ndv = planes[bt * 5 + 4];
            const float frac = (ndv < 1e-8f) ? -1.0f
                               : (float)counts[bt] * (1.0f / 2048.0f);
            if (frac > bc) {
                bn0 = planes[bt*5+0]; bn1 = planes[bt*5+1]; bn2 = planes[bt*5+2];
                bo = planes[bt*5+3]; bc = frac;
            }
        }
        const float sd = ((bn0 * cx + bn1 * cy) + bn2 * cz) - bo;
        zaug[DD + 0] = bn0; zaug[DD + 1] = bn1; zaug[DD + 2] = bn2; zaug[DD + 3] = sd;
        float* normals = out + (BB * DD + BB * KK * DD);
        normals[b*3+0] = bn0; normals[b*3+1] = bn1; normals[b*3+2] = bn2;
        float* offs = normals + BB * 3;
        offs[b] = bo;
        float* conf = offs + BB;
        conf[b] = bc;
    }
    __syncthreads();
    const float* wrow = Wm + (size_t)tid * (DD + 4);
    float acc = bias[tid];
    for (int j = 0; j < DD + 4; ++j) acc += zaug[j] * wrow[j];
    out[b * DD + tid] = acc;
}

extern "C" void kernel_launch(void* const* d_in, const int* in_sizes, int n_in,
                              void* d_out, int out_size, void* d_ws, size_t ws_size,
                              hipStream_t stream) {
    const float* points     = (const float*)d_in[0];
    const float* z_enc      = (const float*)d_in[1];
    const float* z_local    = (const float*)d_in[2];
    // d_in[3] = proxy_coords (unused by reference outputs)
    const int*   sample_idx = (const int*)d_in[4];
    const float* Wm         = (const float*)d_in[5];
    const float* bias       = (const float*)d_in[6];
    float* out = (float*)d_out;

    char* wsb = (char*)d_ws;
    int*   counts = (int*)(wsb + 0);                 // BB*TT ints
    float* planes = (float*)(wsb + BB * TT * 4);     // BB*TT*5 floats

    detect_kernel<<<BB * TT, 512, 0, stream>>>(
        points, sample_idx, z_local, counts, planes, out);
    finalize_kernel<<<BB, 256, 0, stream>>>(
        points, z_enc, Wm, bias, counts, planes, out);
}

// Round 8
// 39.689 us; speedup vs baseline: 1.5565x; 1.2919x over previous
//
#include <hip/hip_runtime.h>

#define BB 8
#define NN 2048
#define TT 64
#define DD 256
#define KK 128

// ---- per-block LDS counting-sort grid ----
#define GSZ 16
#define NC (GSZ * GSZ * GSZ)
#define DTHR 0.053f     // conservative per-dim candidate radius (covers fp error)
#define D2THR 0.0025f   // sqrt(max(d2,0)) < 0.05  <=>  d2 < 0.0025 (exact)

// ---------------------------------------------------------------------------
// One block per (b,t). Counting-sort LDS grid + sorted-order queries.
// Numerics bit-identical to reference (validated r2-r7):
//   d2 = (rsq + pts_sq) - dot(2r, p), non-FMA, left-assoc; d2 < 0.0025f.
// ---------------------------------------------------------------------------
__global__ __launch_bounds__(512) void detect_kernel(
    const float* __restrict__ points, const int* __restrict__ sample_idx,
    const float* __restrict__ z_local,
    int* __restrict__ counts, float* __restrict__ planes,
    float* __restrict__ out)
{
#pragma clang fp contract(off)
    __shared__ float4 sp[NN];        // 32 KB cell-sorted {x,y,z,||p||^2}
    __shared__ int    cellofs[NC];   // 16 KB: hist -> excl start -> end offset
    __shared__ float  sred[8][6];
    __shared__ int    swsum[8];
    __shared__ float  g[6];          // org[3], h[3]
    __shared__ int    blk_cnt;

    const int tid  = threadIdx.x;
    const int lane = tid & 63;
    const int wav  = tid >> 6;
    const int bt   = blockIdx.x;
    const int b    = bt / TT;

    if (tid == 0) blk_cnt = 0;

    const float* P = points + (size_t)b * NN * 3;

    // ---- candidate plane (hoisted: loads overlap staging) ----
    const int i1 = sample_idx[bt * 2 + 0];
    const int i2 = sample_idx[bt * 2 + 1];
    const float q1x = P[i1 * 3 + 0], q1y = P[i1 * 3 + 1], q1z = P[i1 * 3 + 2];
    const float q2x = P[i2 * 3 + 0], q2y = P[i2 * 3 + 1], q2z = P[i2 * 3 + 2];
    const float dx0 = q2x - q1x, dy0 = q2y - q1y, dz0 = q2z - q1z;
    const float nd  = sqrtf((dx0 * dx0 + dy0 * dy0) + dz0 * dz0);
    const float den = nd + 1e-12f;
    const float nx = dx0 / den, ny = dy0 / den, nz = dz0 / den;
    const float e0 = (nx * (q1x + q2x)) * 0.5f;
    const float e1 = (ny * (q1y + q2y)) * 0.5f;
    const float e2 = (nz * (q1z + q2z)) * 0.5f;
    const float off = (e0 + e1) + e2;
    const float nnorm = sqrtf((nx * nx + ny * ny) + nz * nz);
    const float nden  = nnorm + 1e-12f;
    const float nnx = nx / nden, nny = ny / nden, nnz = nz / nden;

    // z_local passthrough slice: 65536 float4 total / 512 blocks = 128 each
    if (tid < 128) {
        const float4* zl = (const float4*)z_local;
        float4* zo = (float4*)(out + BB * DD);
        zo[bt * 128 + tid] = zl[bt * 128 + tid];
    }

    // ---- load 4 points/thread to registers + bbox ----
    float px[4], py[4], pz[4], ps[4];
    float mnx = 3.4e38f, mny = 3.4e38f, mnz = 3.4e38f;
    float mxx = -3.4e38f, mxy = -3.4e38f, mxz = -3.4e38f;
#pragma unroll
    for (int k = 0; k < 4; ++k) {
        const int j = tid + k * 512;
        const float x = P[j * 3 + 0], y = P[j * 3 + 1], z = P[j * 3 + 2];
        px[k] = x; py[k] = y; pz[k] = z;
        ps[k] = (x * x + y * y) + z * z;   // matches pts_sq op order
        mnx = fminf(mnx, x); mxx = fmaxf(mxx, x);
        mny = fminf(mny, y); mxy = fmaxf(mxy, y);
        mnz = fminf(mnz, z); mxz = fmaxf(mxz, z);
    }
#pragma unroll
    for (int o = 32; o > 0; o >>= 1) {
        mnx = fminf(mnx, __shfl_xor(mnx, o));
        mny = fminf(mny, __shfl_xor(mny, o));
        mnz = fminf(mnz, __shfl_xor(mnz, o));
        mxx = fmaxf(mxx, __shfl_xor(mxx, o));
        mxy = fmaxf(mxy, __shfl_xor(mxy, o));
        mxz = fmaxf(mxz, __shfl_xor(mxz, o));
    }
    if (lane == 0) {
        sred[wav][0] = mnx; sred[wav][1] = mny; sred[wav][2] = mnz;
        sred[wav][3] = mxx; sred[wav][4] = mxy; sred[wav][5] = mxz;
    }
    // zero histogram (independent of the reduction)
    for (int c = tid; c < NC; c += 512) cellofs[c] = 0;
    __syncthreads();

    if (tid == 0) {
        float a0 = sred[0][0], a1 = sred[0][1], a2 = sred[0][2];
        float m3 = sred[0][3], m4 = sred[0][4], m5 = sred[0][5];
        for (int w = 1; w < 8; ++w) {
            a0 = fminf(a0, sred[w][0]); a1 = fminf(a1, sred[w][1]); a2 = fminf(a2, sred[w][2]);
            m3 = fmaxf(m3, sred[w][3]); m4 = fmaxf(m4, sred[w][4]); m5 = fmaxf(m5, sred[w][5]);
        }
        g[0] = a0 - 1e-3f; g[1] = a1 - 1e-3f; g[2] = a2 - 1e-3f;
        g[3] = fmaxf((m3 - g[0]) * (1.0f / 15.9f), 0.06f);
        g[4] = fmaxf((m4 - g[1]) * (1.0f / 15.9f), 0.06f);
        g[5] = fmaxf((m5 - g[2]) * (1.0f / 15.9f), 0.06f);
    }
    __syncthreads();
    const float ogx = g[0], ogy = g[1], ogz = g[2];
    const float hx = g[3], hy = g[4], hz = g[5];
    const float ivx = 1.0f / hx, ivy = 1.0f / hy, ivz = 1.0f / hz;

    // ---- histogram ----
    int cell[4];
#pragma unroll
    for (int k = 0; k < 4; ++k) {
        int cx = (int)floorf((px[k] - ogx) * ivx);
        int cy = (int)floorf((py[k] - ogy) * ivy);
        int cz = (int)floorf((pz[k] - ogz) * ivz);
        cx = min(GSZ - 1, max(0, cx));
        cy = min(GSZ - 1, max(0, cy));
        cz = min(GSZ - 1, max(0, cz));
        cell[k] = (cz * GSZ + cy) * GSZ + cx;
        atomicAdd(&cellofs[cell[k]], 1);
    }
    __syncthreads();

    // ---- exclusive prefix sum over NC=4096 cells (8 per thread) ----
    const int base = tid * 8;
    int loc[8];
    int tsum = 0;
#pragma unroll
    for (int k = 0; k < 8; ++k) {
        loc[k] = tsum;                 // thread-local exclusive
        tsum += cellofs[base + k];
    }
    int inc = tsum;                    // inclusive wave scan of thread sums
#pragma unroll
    for (int o = 1; o < 64; o <<= 1) {
        const int v = __shfl_up(inc, o);
        if (lane >= o) inc += v;
    }
    if (lane == 63) swsum[wav] = inc;
    __syncthreads();
    // redundant per-thread prefix over the 8 wave totals (saves a barrier)
    int wbase = 0;
    for (int w = 0; w < wav; ++w) wbase += swsum[w];
    const int texcl = (inc - tsum) + wbase;   // exclusive over threads
#pragma unroll
    for (int k = 0; k < 8; ++k) cellofs[base + k] = texcl + loc[k];  // excl starts
    __syncthreads();

    // ---- scatter: cellofs[c] becomes END offset after all inserts ----
#pragma unroll
    for (int k = 0; k < 4; ++k) {
        const int pos = atomicAdd(&cellofs[cell[k]], 1);
        sp[pos] = make_float4(px[k], py[k], pz[k], ps[k]);
    }
    __syncthreads();   // sorted grid complete

    // ---- queries in SORTED order: reflect + range-scan exact NN match ----
    int cnt = 0;
#pragma unroll
    for (int k = 0; k < 4; ++k) {
        const int n = tid + k * 512;
        const float4 q = sp[n];        // sorted: adjacent lanes share cells
        const float sd = ((q.x * nnx + q.y * nny) + q.z * nnz) - off;
        const float s  = 2.0f * sd;
        const float rx = q.x - s * nnx;
        const float ry = q.y - s * nny;
        const float rz = q.z - s * nnz;
        const float rsq = (rx * rx + ry * ry) + rz * rz;
        const float r2x = rx + rx, r2y = ry + ry, r2z = rz + rz; // exact *2

        const float tx = rx - ogx; const float cfx = floorf(tx * ivx);
        const float ty = ry - ogy; const float cfy = floorf(ty * ivy);
        const float tz = rz - ogz; const float cfz = floorf(tz * ivz);
        const int cxi = (int)cfx, cyi = (int)cfy, czi = (int)cfz;
        const float fx = tx - cfx * hx;
        const float fy = ty - cfy * hy;
        const float fz = tz - cfz * hz;
        // x-window as one contiguous cell-index range
        const int cx0 = max(0, cxi + ((fx < DTHR) ? -1 : 0));
        const int cx1 = min(GSZ - 1, cxi + ((fx > hx - DTHR) ? 1 : 0));
        const int ly = (fy < DTHR) ? -1 : 0, uy = (fy > hy - DTHR) ? 1 : 0;
        const int lz = (fz < DTHR) ? -1 : 0, uz = (fz > hz - DTHR) ? 1 : 0;

        int matched = 0;
        if (cx0 <= cx1) {
            for (int dz = lz; dz <= uz; ++dz) {
                const int cz = czi + dz; if ((unsigned)cz >= GSZ) continue;
                for (int dy = ly; dy <= uy; ++dy) {
                    const int cy = cyi + dy; if ((unsigned)cy >= GSZ) continue;
                    const int rowbase = (cz * GSZ + cy) * GSZ;
                    const int idx0 = rowbase + cx0;
                    const int idx1 = rowbase + cx1;
                    const int jb = (idx0 == 0) ? 0 : cellofs[idx0 - 1];
                    const int je = cellofs[idx1];
                    for (int j = jb; j < je; ++j) {
                        const float4 pm = sp[j];
                        const float c2 = (r2x * pm.x + r2y * pm.y) + r2z * pm.z;
                        const float t1 = rsq + pm.w;
                        matched |= ((t1 - c2) < D2THR) ? 1 : 0;
                    }
                }
            }
        }
        cnt += matched;
    }

    for (int o = 32; o > 0; o >>= 1) cnt += __shfl_down(cnt, o);
    if (lane == 0) atomicAdd(&blk_cnt, cnt);
    __syncthreads();

    if (tid == 0) {
        counts[bt] = blk_cnt;
        planes[bt * 5 + 0] = nx;
        planes[bt * 5 + 1] = ny;
        planes[bt * 5 + 2] = nz;
        planes[bt * 5 + 3] = off;
        planes[bt * 5 + 4] = nd;
    }
}

// ---------------------------------------------------------------------------
// Kernel 2: per-batch finalize, now fully parallel:
//   wave 0: 64 lanes load (count, plane) in ONE latency round; exact argmax
//           (frac = count/2048 exact; max + first-wins via ballot/ffs; winner
//            fields broadcast via shfl) — replaces the serial 64-iter loop.
//   all waves: centroid via shfl partials. Then GEMV.
// ---------------------------------------------------------------------------
__global__ __launch_bounds__(256) void finalize_kernel(
    const float* __restrict__ points, const float* __restrict__ z_enc,
    const float* __restrict__ Wm, const float* __restrict__ bias,
    const int* __restrict__ counts, const float* __restrict__ planes,
    float* __restrict__ out)
{
    const int b = blockIdx.x, tid = threadIdx.x;
    const int lane = tid & 63, wav = tid >> 6;
    __shared__ float zaug[DD + 4];
    __shared__ float swc[4][3];
    __shared__ float sbest[5];

    // centroid partials: 8 pts per thread, wave shfl reduce
    const float* P = points + (size_t)b * NN * 3;
    float sx = 0.f, sy = 0.f, sz = 0.f;
#pragma unroll
    for (int k = 0; k < 8; ++k) {
        const int j = tid + k * 256;
        sx += P[j * 3 + 0]; sy += P[j * 3 + 1]; sz += P[j * 3 + 2];
    }
#pragma unroll
    for (int o = 32; o > 0; o >>= 1) {
        sx += __shfl_xor(sx, o); sy += __shfl_xor(sy, o); sz += __shfl_xor(sz, o);
    }
    if (lane == 0) { swc[wav][0] = sx; swc[wav][1] = sy; swc[wav][2] = sz; }

    zaug[tid] = z_enc[b * DD + tid];

    // wave 0: parallel argmax over the 64 candidates
    if (wav == 0) {
        const int bt = b * TT + lane;
        const float p0 = planes[bt * 5 + 0];
        const float p1 = planes[bt * 5 + 1];
        const float p2 = planes[bt * 5 + 2];
        const float p3 = planes[bt * 5 + 3];
        const float ndv = planes[bt * 5 + 4];
        const int   c  = counts[bt];
        // frac exact: count*(1/2048) with count <= 2^11 -> exact float
        const float frac = (ndv < 1e-8f) ? -1.0f : (float)c * (1.0f / 2048.0f);
        float m = frac;
#pragma unroll
        for (int o = 32; o > 0; o >>= 1) m = fmaxf(m, __shfl_xor(m, o));
        const unsigned long long win = __ballot(frac == m);
        const int first = __ffsll(win) - 1;   // smallest t among maxima
        const float w0 = __shfl(p0, first);
        const float w1 = __shfl(p1, first);
        const float w2 = __shfl(p2, first);
        const float w3 = __shfl(p3, first);
        if (lane == 0) {
            if (m > 0.0f) {
                sbest[0] = w0; sbest[1] = w1; sbest[2] = w2; sbest[3] = w3; sbest[4] = m;
            } else {
                sbest[0] = 0.f; sbest[1] = 1.f; sbest[2] = 0.f; sbest[3] = 0.f; sbest[4] = 0.f;
            }
        }
    }
    __syncthreads();

    if (tid == 0) {
        const float cx = (((swc[0][0] + swc[1][0]) + swc[2][0]) + swc[3][0]) / (float)NN;
        const float cy = (((swc[0][1] + swc[1][1]) + swc[2][1]) + swc[3][1]) / (float)NN;
        const float cz = (((swc[0][2] + swc[1][2]) + swc[2][2]) + swc[3][2]) / (float)NN;
        const float bn0 = sbest[0], bn1 = sbest[1], bn2 = sbest[2];
        const float bo = sbest[3], bc = sbest[4];
        const float sd = ((bn0 * cx + bn1 * cy) + bn2 * cz) - bo;
        zaug[DD + 0] = bn0; zaug[DD + 1] = bn1; zaug[DD + 2] = bn2; zaug[DD + 3] = sd;
        float* normals = out + (BB * DD + BB * KK * DD);
        normals[b * 3 + 0] = bn0; normals[b * 3 + 1] = bn1; normals[b * 3 + 2] = bn2;
        float* offs = normals + BB * 3;
        offs[b] = bo;
        float* conf = offs + BB;
        conf[b] = bc;
    }
    __syncthreads();

    // GEMV: out[b][d] = bias[d] + sum_j zaug[j] * W[d][j]
    const float* wrow = Wm + (size_t)tid * (DD + 4);
    float acc = bias[tid];
    for (int j = 0; j < DD + 4; ++j) acc += zaug[j] * wrow[j];
    out[b * DD + tid] = acc;
}

extern "C" void kernel_launch(void* const* d_in, const int* in_sizes, int n_in,
                              void* d_out, int out_size, void* d_ws, size_t ws_size,
                              hipStream_t stream) {
    const float* points     = (const float*)d_in[0];
    const float* z_enc      = (const float*)d_in[1];
    const float* z_local    = (const float*)d_in[2];
    // d_in[3] = proxy_coords (unused by reference outputs)
    const int*   sample_idx = (const int*)d_in[4];
    const float* Wm         = (const float*)d_in[5];
    const float* bias       = (const float*)d_in[6];
    float* out = (float*)d_out;

    char* wsb = (char*)d_ws;
    int*   counts = (int*)(wsb + 0);                 // BB*TT ints
    float* planes = (float*)(wsb + BB * TT * 4);     // BB*TT*5 floats

    detect_kernel<<<BB * TT, 512, 0, stream>>>(
        points, sample_idx, z_local, counts, planes, out);
    finalize_kernel<<<BB, 256, 0, stream>>>(
        points, z_enc, Wm, bias, counts, planes, out);
}